// Round 1
// baseline (261.201 us; speedup 1.0000x reference)
//
#include <hip/hip_runtime.h>
#include <math.h>

#define ALPHA  0.1f
#define DT     0.01f
#define EPSV   1e-9f
#define DIFF   10.0f
#define HARD_P 1.5707963267948966f

#define CHUNK 16

// Pre-pass: g[i] = e^{-i*phase[i]} * (x_i + i*y_i); also copy xy -> out[3N:5N]
__global__ void node_pre(const float2* __restrict__ xy,
                         const float*  __restrict__ phase,
                         float2* __restrict__ g,
                         float2* __restrict__ out_xyold,
                         int n) {
    int i = blockIdx.x * blockDim.x + threadIdx.x;
    if (i >= n) return;
    float2 p = xy[i];
    float ph = phase[i];
    float s, c;
    sincosf(ph, &s, &c);
    // e^{-i ph} * (x + iy) = (x c + y s) + i (y c - x s)
    float2 gv;
    gv.x = p.x * c + p.y * s;
    gv.y = p.y * c - p.x * s;
    g[i] = gv;
    out_xyold[i] = p;   // xy_dot_old_new = xy
}

// Edge pass: each thread owns CHUNK consecutive (sorted-by-src) edges,
// run-accumulates g[dst] per src segment, atomics only at segment changes.
__global__ __launch_bounds__(256) void edge_kernel(
        const int* __restrict__ src,
        const int* __restrict__ dst,
        const float2* __restrict__ g,
        float* __restrict__ Gsum,
        int n_edges) {
    int t = blockIdx.x * blockDim.x + threadIdx.x;
    int base = t * CHUNK;
    if (base >= n_edges) return;

    if (base + CHUNK <= n_edges) {
        // vectorized loads: 4x int4 for src and dst
        const int4* src4 = (const int4*)(src + base);
        const int4* dst4 = (const int4*)(dst + base);
        int s_arr[CHUNK], d_arr[CHUNK];
        #pragma unroll
        for (int q = 0; q < CHUNK / 4; ++q) {
            int4 sv = src4[q];
            int4 dv = dst4[q];
            s_arr[4*q+0] = sv.x; s_arr[4*q+1] = sv.y; s_arr[4*q+2] = sv.z; s_arr[4*q+3] = sv.w;
            d_arr[4*q+0] = dv.x; d_arr[4*q+1] = dv.y; d_arr[4*q+2] = dv.z; d_arr[4*q+3] = dv.w;
        }
        int cur = s_arr[0];
        float2 g0 = g[d_arr[0]];
        float ax = g0.x, ay = g0.y;
        #pragma unroll
        for (int k = 1; k < CHUNK; ++k) {
            float2 gd = g[d_arr[k]];
            int s = s_arr[k];
            if (s != cur) {
                atomicAdd(&Gsum[2*cur],   ax);
                atomicAdd(&Gsum[2*cur+1], ay);
                cur = s; ax = gd.x; ay = gd.y;
            } else {
                ax += gd.x; ay += gd.y;
            }
        }
        atomicAdd(&Gsum[2*cur],   ax);
        atomicAdd(&Gsum[2*cur+1], ay);
    } else {
        // scalar tail
        int cur = -1;
        float ax = 0.f, ay = 0.f;
        for (int e = base; e < n_edges; ++e) {
            int s = src[e];
            float2 gd = g[dst[e]];
            if (s != cur) {
                if (cur >= 0) {
                    atomicAdd(&Gsum[2*cur],   ax);
                    atomicAdd(&Gsum[2*cur+1], ay);
                }
                cur = s; ax = gd.x; ay = gd.y;
            } else {
                ax += gd.x; ay += gd.y;
            }
        }
        if (cur >= 0) {
            atomicAdd(&Gsum[2*cur],   ax);
            atomicAdd(&Gsum[2*cur+1], ay);
        }
    }
}

// Post-pass: per-node dynamics + rotate accumulated sum by e^{+i*phase}
__global__ void node_post(const float2* __restrict__ xy,
                          const float2* __restrict__ xyd,
                          const float*  __restrict__ phase,
                          const float*  __restrict__ w,
                          const float*  __restrict__ amps,
                          const float*  __restrict__ ha,
                          const float*  __restrict__ Gsum,
                          float* __restrict__ out,
                          int n) {
    int i = blockIdx.x * blockDim.x + threadIdx.x;
    if (i >= n) return;
    float2 p  = xy[i];
    float2 pdv = xyd[i];
    float x = p.x, y = p.y;
    float xd = pdv.x, yd = pdv.y;

    float r2 = x*x + y*y;
    float a = ALPHA * (1.0f - r2*r2);
    float h = ha[i];
    float zeta = 1.0f - h * ((xd + EPSV) / (fabsf(xd) + EPSV));
    float b = w[i] / (zeta + EPSV);
    float kx = a*x - b*y;
    float ky = b*x + a*y;

    float gx = Gsum[2*i], gy = Gsum[2*i+1];
    float s, c;
    sincosf(phase[i], &s, &c);
    float sumx = c*gx - s*gy;
    float sumy = s*gx + c*gy;

    float xdot = fminf(fmaxf(kx + sumx, xd - DIFF), xd + DIFF);
    float ydot = fminf(fmaxf(ky + sumy, yd - DIFF), yd + DIFF);
    float xn = x + xdot * DT;
    float yn = y + ydot * DT;

    float ang = fminf(fmaxf(amps[i] * yn, -HARD_P), HARD_P);

    out[i] = ang;                         // angles
    float2* xy_new = (float2*)(out + n);  // xy_new, interleaved (N,2)
    float2 v; v.x = xn; v.y = yn;
    xy_new[i] = v;
}

extern "C" void kernel_launch(void* const* d_in, const int* in_sizes, int n_in,
                              void* d_out, int out_size, void* d_ws, size_t ws_size,
                              hipStream_t stream) {
    const float2* xy    = (const float2*)d_in[0];
    const float2* xyd   = (const float2*)d_in[1];
    const float*  phase = (const float*)d_in[2];
    const float*  w     = (const float*)d_in[3];
    const float*  amps  = (const float*)d_in[4];
    const float*  ha    = (const float*)d_in[5];
    const int*    esrc  = (const int*)d_in[6];
    const int*    edst  = (const int*)d_in[7];

    const int n       = in_sizes[2];
    const int n_edges = in_sizes[6];

    float* out = (float*)d_out;

    // workspace layout: g (float2[n]) | Gsum (float[2n])
    float2* g    = (float2*)d_ws;
    float*  Gsum = (float*)((char*)d_ws + (size_t)n * sizeof(float2));

    hipMemsetAsync(Gsum, 0, (size_t)2 * n * sizeof(float), stream);

    const int B = 256;
    node_pre<<<(n + B - 1) / B, B, 0, stream>>>(xy, phase, g, (float2*)(out + (size_t)3 * n), n);

    int n_threads = (n_edges + CHUNK - 1) / CHUNK;
    edge_kernel<<<(n_threads + B - 1) / B, B, 0, stream>>>(esrc, edst, g, Gsum, n_edges);

    node_post<<<(n + B - 1) / B, B, 0, stream>>>(xy, xyd, phase, w, amps, ha, Gsum, out, n);
}

// Round 2
// 231.774 us; speedup vs baseline: 1.1270x; 1.1270x over previous
//
#include <hip/hip_runtime.h>
#include <math.h>

#define ALPHA  0.1f
#define DT     0.01f
#define EPSV   1e-9f
#define DIFF   10.0f
#define HARD_P 1.5707963267948966f

#define CHUNK 16

// Pre-pass: g[i] = e^{-i*phase[i]} * (x_i + i*y_i); copy xy -> out[3N:5N];
// zero Gsum (replaces separate memset dispatch).
__global__ void node_pre(const float2* __restrict__ xy,
                         const float*  __restrict__ phase,
                         float2* __restrict__ g,
                         float2* __restrict__ out_xyold,
                         float2* __restrict__ Gsum,
                         int n) {
    int i = blockIdx.x * blockDim.x + threadIdx.x;
    if (i >= n) return;
    float2 p = xy[i];
    float ph = phase[i];
    float s, c;
    sincosf(ph, &s, &c);
    // e^{-i ph} * (x + iy) = (x c + y s) + i (y c - x s)
    float2 gv;
    gv.x = p.x * c + p.y * s;
    gv.y = p.y * c - p.x * s;
    g[i] = gv;
    out_xyold[i] = p;   // xy_dot_old_new = xy
    float2 z; z.x = 0.f; z.y = 0.f;
    Gsum[i] = z;
}

// Edge pass: each thread owns CHUNK consecutive (sorted-by-src) edges.
// All CHUNK gathers are prefetched into registers FIRST (16 independent
// L2 loads in flight), then the segment-accumulation runs from registers.
__global__ __launch_bounds__(256) void edge_kernel(
        const int* __restrict__ src,
        const int* __restrict__ dst,
        const float2* __restrict__ g,
        float* __restrict__ Gsum,
        int n_edges) {
    int t = blockIdx.x * blockDim.x + threadIdx.x;
    int base = t * CHUNK;
    if (base >= n_edges) return;

    if (base + CHUNK <= n_edges) {
        const int4* src4 = (const int4*)(src + base);
        const int4* dst4 = (const int4*)(dst + base);
        int s_arr[CHUNK], d_arr[CHUNK];
        #pragma unroll
        for (int q = 0; q < CHUNK / 4; ++q) {
            int4 sv = src4[q];
            int4 dv = dst4[q];
            s_arr[4*q+0] = sv.x; s_arr[4*q+1] = sv.y; s_arr[4*q+2] = sv.z; s_arr[4*q+3] = sv.w;
            d_arr[4*q+0] = dv.x; d_arr[4*q+1] = dv.y; d_arr[4*q+2] = dv.z; d_arr[4*q+3] = dv.w;
        }

        // ---- prefetch: all gathers issued before any use ----
        float gx[CHUNK], gy[CHUNK];
        #pragma unroll
        for (int k = 0; k < CHUNK; ++k) {
            float2 t2 = g[d_arr[k]];
            gx[k] = t2.x; gy[k] = t2.y;
        }

        // ---- segment accumulation from registers ----
        int cur = s_arr[0];
        float ax = gx[0], ay = gy[0];
        #pragma unroll
        for (int k = 1; k < CHUNK; ++k) {
            int s = s_arr[k];
            if (s != cur) {
                atomicAdd(&Gsum[2*cur],   ax);
                atomicAdd(&Gsum[2*cur+1], ay);
                cur = s; ax = gx[k]; ay = gy[k];
            } else {
                ax += gx[k]; ay += gy[k];
            }
        }
        atomicAdd(&Gsum[2*cur],   ax);
        atomicAdd(&Gsum[2*cur+1], ay);
    } else {
        // scalar tail
        int cur = -1;
        float ax = 0.f, ay = 0.f;
        for (int e = base; e < n_edges; ++e) {
            int s = src[e];
            float2 gd = g[dst[e]];
            if (s != cur) {
                if (cur >= 0) {
                    atomicAdd(&Gsum[2*cur],   ax);
                    atomicAdd(&Gsum[2*cur+1], ay);
                }
                cur = s; ax = gd.x; ay = gd.y;
            } else {
                ax += gd.x; ay += gd.y;
            }
        }
        if (cur >= 0) {
            atomicAdd(&Gsum[2*cur],   ax);
            atomicAdd(&Gsum[2*cur+1], ay);
        }
    }
}

// Post-pass: per-node dynamics + rotate accumulated sum by e^{+i*phase}
__global__ void node_post(const float2* __restrict__ xy,
                          const float2* __restrict__ xyd,
                          const float*  __restrict__ phase,
                          const float*  __restrict__ w,
                          const float*  __restrict__ amps,
                          const float*  __restrict__ ha,
                          const float*  __restrict__ Gsum,
                          float* __restrict__ out,
                          int n) {
    int i = blockIdx.x * blockDim.x + threadIdx.x;
    if (i >= n) return;
    float2 p  = xy[i];
    float2 pdv = xyd[i];
    float x = p.x, y = p.y;
    float xd = pdv.x, yd = pdv.y;

    float r2 = x*x + y*y;
    float a = ALPHA * (1.0f - r2*r2);
    float h = ha[i];
    float zeta = 1.0f - h * ((xd + EPSV) / (fabsf(xd) + EPSV));
    float b = w[i] / (zeta + EPSV);
    float kx = a*x - b*y;
    float ky = b*x + a*y;

    float gx = Gsum[2*i], gy = Gsum[2*i+1];
    float s, c;
    sincosf(phase[i], &s, &c);
    float sumx = c*gx - s*gy;
    float sumy = s*gx + c*gy;

    float xdot = fminf(fmaxf(kx + sumx, xd - DIFF), xd + DIFF);
    float ydot = fminf(fmaxf(ky + sumy, yd - DIFF), yd + DIFF);
    float xn = x + xdot * DT;
    float yn = y + ydot * DT;

    float ang = fminf(fmaxf(amps[i] * yn, -HARD_P), HARD_P);

    out[i] = ang;                         // angles
    float2* xy_new = (float2*)(out + n);  // xy_new, interleaved (N,2)
    float2 v; v.x = xn; v.y = yn;
    xy_new[i] = v;
}

extern "C" void kernel_launch(void* const* d_in, const int* in_sizes, int n_in,
                              void* d_out, int out_size, void* d_ws, size_t ws_size,
                              hipStream_t stream) {
    const float2* xy    = (const float2*)d_in[0];
    const float2* xyd   = (const float2*)d_in[1];
    const float*  phase = (const float*)d_in[2];
    const float*  w     = (const float*)d_in[3];
    const float*  amps  = (const float*)d_in[4];
    const float*  ha    = (const float*)d_in[5];
    const int*    esrc  = (const int*)d_in[6];
    const int*    edst  = (const int*)d_in[7];

    const int n       = in_sizes[2];
    const int n_edges = in_sizes[6];

    float* out = (float*)d_out;

    // workspace layout: g (float2[n]) | Gsum (float[2n])
    float2* g    = (float2*)d_ws;
    float*  Gsum = (float*)((char*)d_ws + (size_t)n * sizeof(float2));

    const int B = 256;
    node_pre<<<(n + B - 1) / B, B, 0, stream>>>(xy, phase, g,
                                                (float2*)(out + (size_t)3 * n),
                                                (float2*)Gsum, n);

    int n_threads = (n_edges + CHUNK - 1) / CHUNK;
    edge_kernel<<<(n_threads + B - 1) / B, B, 0, stream>>>(esrc, edst, g, Gsum, n_edges);

    node_post<<<(n + B - 1) / B, B, 0, stream>>>(xy, xyd, phase, w, amps, ha, Gsum, out, n);
}